// Round 6
// baseline (288.633 us; speedup 1.0000x reference)
//
#include <hip/hip_runtime.h>
#include <math.h>

// MultiHeadBigBirdAttention: B=2, S=2048, E=1024, H=8, DH=128
// Pipeline (bf16 MFMA 16x16x32):
//   1. prep: fused {q,k,v fp32->bf16} + {W* fp32 [K][N] -> bf16 W^T [N][K]}
//   2. gemm_k<0> (grid 32x8x3): projections -> Qh/Kh [B,H,S,DH], Vt [B,H,DH,S]
//   3. flash_k: static-max flash -> ctx bf16
//   4. gemm_k<1>: ctx @ Wo^T + bo -> d_out fp32
//
// MFMA layouts (verified learn_hip m89/m91/m120):
//   C/D: col = lane&15, row = (lane>>4)*4 + reg
//   A:   m   = lane&15, k   = (lane>>4)*8 + j
//   B:   n   = lane&15, k   = (lane>>4)*8 + j
//
// R14: flash occupancy rework. R13 showed flash is LATENCY-bound at
// 2 waves/SIMD (halving LDS reads gave only -6%; 3750 cyc/block-iter vs
// ~700 issue): 512 blocks x 4 waves caps the chip at 2048 waves. This
// round: 1024 blocks (QBLK=32 rows) x 4 waves; wave (r,kh) = 16 rows x
// 32 keys. V is no longer staged in LDS: each wave loads its own 8 V
// B-fragments global->reg at iter top (L2-resident, consumed at PV).
// LDS = K dbuf 32KB + P 5KB = 37888B -> 4 blocks/CU; launch_bounds(256,4)
// -> 4 waves/SIMD (2x TLP). K staging, XOR swizzles, 1-barrier/iter
// skeleton, rt<->63-rt pairing and bh-low-bits XCD locality all unchanged.

typedef __bf16 bf16_t;
typedef __bf16 bf16x8 __attribute__((ext_vector_type(8)));
typedef float f32x4 __attribute__((ext_vector_type(4)));

#define MFMA16(a, b, c) __builtin_amdgcn_mfma_f32_16x16x32_bf16(a, b, c, 0, 0, 0)

// ---------------------------------------------------------------------------
// prep: blocks 0..6143 convert q/k/v fp32->bf16 (8 elems/thread);
//       blocks 6144..10239 transpose the 4 weight matrices to bf16 W^T.
// ---------------------------------------------------------------------------
__global__ __launch_bounds__(256) void prep(const float* q, const float* k,
                                            const float* v, bf16_t* qb,
                                            bf16_t* kb, bf16_t* vb,
                                            const float* W0, const float* W1,
                                            const float* W2, const float* W3,
                                            bf16_t* Wt) {
  const int bid = blockIdx.x, tid = threadIdx.x;
  if (bid < 6144) {
    const int z = bid >> 11, chunk = bid & 2047;
    const float* x = (z == 0) ? q : (z == 1) ? k : v;
    bf16_t* y = (z == 0) ? qb : (z == 1) ? kb : vb;
    size_t i = ((size_t)chunk * 256 + tid) * 8;
    float4 a = *(const float4*)(x + i);
    float4 b = *(const float4*)(x + i + 4);
    bf16x8 o = {(bf16_t)a.x, (bf16_t)a.y, (bf16_t)a.z, (bf16_t)a.w,
                (bf16_t)b.x, (bf16_t)b.y, (bf16_t)b.z, (bf16_t)b.w};
    *(bf16x8*)(y + i) = o;
  } else {
    __shared__ float t[32][33];
    const int b2 = bid - 6144;
    const int wz = b2 >> 10, t2 = b2 & 1023;
    const float* W = (wz == 0) ? W0 : (wz == 1) ? W1 : (wz == 2) ? W2 : W3;
    bf16_t* o = Wt + (size_t)wz * 1024 * 1024;
    const int n0 = (t2 & 31) * 32, k0 = (t2 >> 5) * 32;
    const int tx = tid & 31, ty = tid >> 5;
#pragma unroll
    for (int i = 0; i < 4; i++)
      t[ty + 8 * i][tx] = W[(size_t)(k0 + ty + 8 * i) * 1024 + n0 + tx];
    __syncthreads();
#pragma unroll
    for (int i = 0; i < 4; i++)
      o[(size_t)(n0 + ty + 8 * i) * 1024 + k0 + tx] = (bf16_t)t[tx][ty + 8 * i];
  }
}

// ---------------------------------------------------------------------------
// GEMM 128x128 tile, BK=64, LDS double-buffered, register-staged pipeline
// (R8 skeleton, proven). Grid mapping: bm = blockIdx.x (32), bn = blockIdx.y
// (8) -> XCD = bm%8; per-XCD L2 working set = 4 A-tiles (1MB) + W^T (2MB).
// ---------------------------------------------------------------------------
template <int MODE>
__global__ __launch_bounds__(256) void gemm_k(
    const bf16_t* qb, const bf16_t* kb, const bf16_t* vb, const bf16_t* Wt,
    const float* b0, const float* b1, const float* b2, bf16_t* Qh, bf16_t* Kh,
    bf16_t* Vt, float* Of32) {
  __shared__ bf16_t As[2][128 * 64];
  __shared__ bf16_t Bs[2][128 * 64];
  const int tid = threadIdx.x, w = tid >> 6, lane = tid & 63;
  const int bm = blockIdx.x, bn = blockIdx.y;  // swapped: XCD = bm%8
  const int wr = w >> 1, wc = w & 1, q4 = lane >> 4, lo = lane & 15;
  const int z = (MODE == 0) ? blockIdx.z : 3;
  const bf16_t* A = (MODE == 1) ? qb : (z == 0) ? qb : (z == 1) ? kb : vb;
  const bf16_t* Bt = Wt + (size_t)z * 1024 * 1024;
  const float* bias = (MODE == 1) ? b0 : (z == 0) ? b0 : (z == 1) ? b1 : b2;

  f32x4 acc[4][4];
#pragma unroll
  for (int m = 0; m < 4; m++)
#pragma unroll
    for (int n = 0; n < 4; n++) acc[m][n] = (f32x4){0.f, 0.f, 0.f, 0.f};

  const int r2 = tid >> 1;         // 0..127
  const int cb = (tid & 1) * 4;    // chunk base 0 / 4
  const bf16_t* Arow = A + (size_t)(bm * 128 + r2) * 1024;
  const bf16_t* Brow = Bt + (size_t)(bn * 128 + r2) * 1024;

  bf16x8 ar[4], br[4];
  auto loadAB = [&](int k0) {
#pragma unroll
    for (int i = 0; i < 4; i++) {
      ar[i] = *(const bf16x8*)(Arow + k0 + (cb + i) * 8);
      br[i] = *(const bf16x8*)(Brow + k0 + (cb + i) * 8);
    }
  };

  loadAB(0);
  for (int k = 0; k < 16; k++) {
    const int cur = k & 1;
    // deposit tile k (waits only on its own global loads)
#pragma unroll
    for (int i = 0; i < 4; i++) {
      *(bf16x8*)&As[cur][r2 * 64 + (((cb + i) ^ (r2 & 7)) * 8)] = ar[i];
      *(bf16x8*)&Bs[cur][r2 * 64 + (((cb + i) ^ (r2 & 7)) * 8)] = br[i];
    }
    // prefetch tile k+1 into private regs (in flight through barrier+compute)
    if (k < 15) loadAB((k + 1) * 64);
    __syncthreads();

#pragma unroll
    for (int kc = 0; kc < 2; kc++) {
      bf16x8 af[4], bfr[4];
#pragma unroll
      for (int m = 0; m < 4; m++) {
        int rr = wr * 64 + m * 16 + lo;
        af[m] = *(const bf16x8*)&As[cur][rr * 64 + (((kc * 4 + q4) ^ (rr & 7)) * 8)];
      }
#pragma unroll
      for (int n = 0; n < 4; n++) {
        int rr = wc * 64 + n * 16 + lo;
        bfr[n] = *(const bf16x8*)&Bs[cur][rr * 64 + (((kc * 4 + q4) ^ (rr & 7)) * 8)];
      }
#pragma unroll
      for (int m = 0; m < 4; m++)
#pragma unroll
        for (int n = 0; n < 4; n++)
          acc[m][n] = MFMA16(af[m], bfr[n], acc[m][n]);
    }
    // no trailing barrier: dbuf + top-of-iter deposit make it safe
  }

#pragma unroll
  for (int m = 0; m < 4; m++) {
#pragma unroll
    for (int n = 0; n < 4; n++) {
      int rowg0 = bm * 128 + wr * 64 + m * 16 + q4 * 4;
      int colg = bn * 128 + wc * 64 + n * 16 + lo;
      float bv = bias[colg];
#pragma unroll
      for (int rg = 0; rg < 4; rg++) {
        float val = acc[m][n][rg] + bv;
        int row = rowg0 + rg;
        if (MODE == 1) {
          Of32[(size_t)row * 1024 + colg] = val;
        } else {
          int b = row >> 11, s = row & 2047;  // S=2048
          int h = colg >> 7, d = colg & 127;  // DH=128
          if (z == 0)
            Qh[(((size_t)(b * 8 + h)) * 2048 + s) * 128 + d] = (bf16_t)val;
          else if (z == 1)
            Kh[(((size_t)(b * 8 + h)) * 2048 + s) * 128 + d] = (bf16_t)val;
          else
            Vt[(((size_t)(b * 8 + h)) * 128 + d) * 2048 + s] = (bf16_t)val;
        }
      }
    }
  }
}

// ---------------------------------------------------------------------------
// Flash attention v8: 1024 blocks (16 bh x 64 row-tiles of 32 rows),
// 4 waves; wave (r=w>>1, kh=w&1) owns rows r*16..+15 x keys kh*32..+31.
// K: reg-staged double-buffered LDS (R8 skeleton, 1 barrier/iter).
// V: direct global->reg per wave (8 bf16x8 loads at iter top, consumed at
// PV; L2-resident, XCD-local via bh%8). P wave-private [16][40].
// rt<->(63-rt) pairing for causal balance. kh-half combine via dead K-dbuf.
// ---------------------------------------------------------------------------
__global__ __launch_bounds__(256, 4) void flash_k(const bf16_t* Qh,
                                                  const bf16_t* Kh,
                                                  const bf16_t* Vt, bf16_t* ctx,
                                                  const int* causal_p) {
  __shared__ bf16_t sm[16384 + 4 * 640];  // K dbuf 32KB + P 5KB
  const int tid = threadIdx.x, w = tid >> 6, lane = tid & 63;
  const int q4 = lane >> 4, lo = lane & 15;
  const int r = w >> 1, kh = w & 1;  // row-group (16 rows), key-half (32 keys)
  const int n0 = blockIdx.x;
  const int u = n0 & 511, hi = n0 >> 9;
  const int bh = u & 15, p0 = u >> 4;       // bh in low bits: XCD = bh%8
  const int rt = hi ? (63 - p0) : p0;       // 32-row Q tile, 0..63
  const int causal = *causal_p;
  const int kmax = causal ? (rt >> 1) : 31;

  bf16_t* Ps = sm + 16384 + w * 640;  // [16 rows][40]

  // Q fragments: rows rt*32 + r*16 + lo, dh chunk ks*32 + q4*8.
  bf16x8 aq[4];
  {
    const bf16_t* qa =
        Qh + ((size_t)bh * 2048 + rt * 32 + r * 16 + lo) * 128;
#pragma unroll
    for (int ks = 0; ks < 4; ks++)
      aq[ks] = *(const bf16x8*)(qa + ks * 32 + q4 * 8);
  }

  const bf16_t* Kbase = Kh + (size_t)bh * 2048 * 128;
  // V B-fragment base: row d = n*16 + lo, keys kt*64 + kh*32 + q4*8..+7.
  const bf16_t* Vb = Vt + ((size_t)bh * 128 + lo) * 2048 + kh * 32 + q4 * 8;
  const int kr = tid >> 2, kc = (tid & 3) * 4;

  bf16x8 kreg[4], vreg[8];
  auto loadK = [&](int kt) {
    const bf16_t* kp = Kbase + (size_t)(kt * 64 + kr) * 128;
#pragma unroll
    for (int i = 0; i < 4; i++) kreg[i] = *(const bf16x8*)(kp + (kc + i) * 8);
  };
  auto loadV = [&](int kt) {
#pragma unroll
    for (int n = 0; n < 8; n++)
      vreg[n] = *(const bf16x8*)(Vb + (size_t)n * (16 * 2048) + kt * 64);
  };

  f32x4 acc[8], lacc;
#pragma unroll
  for (int i = 0; i < 8; i++) acc[i] = (f32x4){0.f, 0.f, 0.f, 0.f};
  lacc = (f32x4){0.f, 0.f, 0.f, 0.f};

  const bf16_t one = (bf16_t)1.0f;
  const bf16x8 vone = {one, one, one, one, one, one, one, one};
  const float sc2 = 0.08838834764831845f * 1.44269504088896f;

  loadK(0);
  for (int kt = 0; kt <= kmax; ++kt) {
    bf16_t* Kd = sm + (kt & 1) * 8192;
    // deposit K tile kt (waits only on its own global loads)
#pragma unroll
    for (int i = 0; i < 4; i++)
      *(bf16x8*)&Kd[kr * 128 + (((kc + i) ^ (kr & 7)) * 8)] = kreg[i];
    if (kt < kmax) loadK(kt + 1);  // in flight through barrier+compute
    loadV(kt);                     // in flight until PV (QK^T+softmax slack)
    __syncthreads();

    // ---- QK^T: [16 rows x 32 keys] per wave ----
    f32x4 sa[2];
#pragma unroll
    for (int nt = 0; nt < 2; nt++) sa[nt] = (f32x4){0.f, 0.f, 0.f, 0.f};
#pragma unroll
    for (int ks = 0; ks < 4; ks++) {
#pragma unroll
      for (int nt = 0; nt < 2; nt++) {
        int key = kh * 32 + nt * 16 + lo;
        bf16x8 bk =
            *(const bf16x8*)&Kd[key * 128 + (((ks * 4 + q4) ^ (key & 7)) * 8)];
        sa[nt] = MFMA16(aq[ks], bk, sa[nt]);
      }
    }

    // ---- softmax numerator -> wave-private P [16 rows x 32 keys] ----
    const bool diag = causal && (kt == kmax);
#pragma unroll
    for (int nt = 0; nt < 2; nt++) {
      int keyg = kt * 64 + kh * 32 + nt * 16 + lo;
#pragma unroll
      for (int rg = 0; rg < 4; rg++) {
        int rowg = rt * 32 + r * 16 + q4 * 4 + rg;
        float pv = exp2f(sa[nt][rg] * sc2);
        if (diag && keyg > rowg) pv = 0.f;
        Ps[(q4 * 4 + rg) * 40 + nt * 16 + lo] = (bf16_t)pv;
      }
    }

    // ---- P fragment (K=32 = wave's whole key-half), row-sum, PV ----
    bf16x8 ap = *(const bf16x8*)&Ps[lo * 40 + q4 * 8];
    lacc = MFMA16(ap, vone, lacc);
#pragma unroll
    for (int n = 0; n < 8; n++) acc[n] = MFMA16(ap, vreg[n], acc[n]);
  }

  // ---- combine key-half partials (once per block) ----
  __syncthreads();  // K dbuf now dead; all Ps reads done
  float* farena = (float*)sm;  // 8192 floats = 32KB (K dbuf region)
  if (kh == 1) {
    int base = r * 4096 + lane * 64;
#pragma unroll
    for (int n = 0; n < 8; n++)
      *(f32x4*)&farena[base + ((n ^ (lane & 15)) & 15) * 4] = acc[n];
    float* lp = (float*)(sm + 16384 + w * 640);
    *(f32x4*)&lp[lane * 4] = lacc;
  }
  __syncthreads();
  if (kh == 0) {
    int base = r * 4096 + lane * 64;
    float* lp = (float*)(sm + 16384 + (w + 1) * 640);
    lacc += *(const f32x4*)&lp[lane * 4];
#pragma unroll
    for (int n = 0; n < 8; n++)
      acc[n] += *(const f32x4*)&farena[base + ((n ^ (lane & 15)) & 15) * 4];
    int b = bh >> 3, h = bh & 7;
#pragma unroll
    for (int rg = 0; rg < 4; rg++) {
      float inv = 1.f / lacc[rg];
      int row = b * 2048 + rt * 32 + r * 16 + q4 * 4 + rg;
#pragma unroll
      for (int n = 0; n < 8; n++)
        ctx[(size_t)row * 1024 + h * 128 + n * 16 + lo] =
            (bf16_t)(acc[n][rg] * inv);
    }
  }
}

// ---------------------------------------------------------------------------
extern "C" void kernel_launch(void* const* d_in, const int* in_sizes, int n_in,
                              void* d_out, int out_size, void* d_ws,
                              size_t ws_size, hipStream_t stream) {
  const float* q = (const float*)d_in[0];
  const float* k = (const float*)d_in[1];
  const float* v = (const float*)d_in[2];
  const float* Wq = (const float*)d_in[3];
  const float* bq = (const float*)d_in[4];
  const float* Wk = (const float*)d_in[5];
  const float* bk = (const float*)d_in[6];
  const float* Wv = (const float*)d_in[7];
  const float* bv = (const float*)d_in[8];
  const float* Wo = (const float*)d_in[9];
  const float* bo = (const float*)d_in[10];
  const int* isc = (const int*)d_in[11];

  char* ws = (char*)d_ws;
  bf16_t* Wt = (bf16_t*)ws;                     // 8MB: W^T bf16 x4
  bf16_t* qb = (bf16_t*)(ws + (8ull << 20));    // 8MB
  bf16_t* kb = (bf16_t*)(ws + (16ull << 20));   // 8MB
  bf16_t* vb = (bf16_t*)(ws + (24ull << 20));   // 8MB
  bf16_t* Qh = (bf16_t*)(ws + (32ull << 20));   // 8MB [B,H,S,DH]
  bf16_t* Kh = (bf16_t*)(ws + (40ull << 20));   // 8MB [B,H,S,DH]
  bf16_t* Vt = (bf16_t*)(ws + (48ull << 20));   // 8MB [B,H,DH,S]
  bf16_t* ctx = (bf16_t*)(ws + (8ull << 20));   // reuse qb

  prep<<<dim3(10240), 256, 0, stream>>>(q, k, v, qb, kb, vb, Wq, Wk, Wv, Wo, Wt);

  gemm_k<0><<<dim3(32, 8, 3), 256, 0, stream>>>(qb, kb, vb, Wt, bq, bk, bv, Qh,
                                                Kh, Vt, nullptr);

  flash_k<<<dim3(1024), 256, 0, stream>>>(Qh, Kh, Vt, ctx, isc);

  gemm_k<1><<<dim3(32, 8), 256, 0, stream>>>(ctx, nullptr, nullptr, Wt, bo,
                                             nullptr, nullptr, nullptr, nullptr,
                                             nullptr, (float*)d_out);
}

// Round 7
// 258.360 us; speedup vs baseline: 1.1172x; 1.1172x over previous
//
#include <hip/hip_runtime.h>
#include <math.h>

// MultiHeadBigBirdAttention: B=2, S=2048, E=1024, H=8, DH=128
// Pipeline (bf16 MFMA 16x16x32):
//   1. prep: {W* fp32 [K][N] -> bf16 W^T [N][K]} only (qkv conversion fused
//      into gemm0 staging as of R15)
//   2. gemm_k<0> (grid 32x8x3): fp32 q/k/v @ W^T -> Qh/Kh [B,H,S,DH],
//      Vt [B,H,DH,S] (A converted fp32->bf16 in registers during deposit)
//   3. flash_k: static-max flash (R13 structure, proven 51.5us) -> ctx bf16
//   4. gemm_k<1>: ctx(bf16) @ Wo^T + bo -> d_out fp32
//
// MFMA layouts (verified learn_hip m89/m91/m120):
//   C/D: col = lane&15, row = (lane>>4)*4 + reg
//   A:   m   = lane&15, k   = (lane>>4)*8 + j
//   B:   n   = lane&15, k   = (lane>>4)*8 + j
//
// R15:
//   - flash_k: REVERT to R13 exactly (key-split waves, 51.5us). R14's
//     occupancy push spilled: launch_bounds(256,4) forced VGPR=64 against
//     ~110 demand -> scratch traffic (WRITE_SIZE 8->45MB). Register budget
//     must close before occupancy can rise; it doesn't for this kernel.
//   - prep: qkv fp32->bf16 pass DELETED (was 72MB traffic + 24MB re-read).
//     gemm_k<0> reads fp32 A directly and converts in-register at deposit
//     (same (bf16_t) cast -> bit-identical A). Net HBM -48MB + one fewer
//     kernel. prep keeps only the W^T transpose (4096 blocks).

typedef __bf16 bf16_t;
typedef __bf16 bf16x8 __attribute__((ext_vector_type(8)));
typedef float f32x4 __attribute__((ext_vector_type(4)));

#define MFMA16(a, b, c) __builtin_amdgcn_mfma_f32_16x16x32_bf16(a, b, c, 0, 0, 0)

// ---------------------------------------------------------------------------
// prep: transpose the 4 weight matrices to bf16 W^T. 4096 blocks.
// ---------------------------------------------------------------------------
__global__ __launch_bounds__(256) void prep(const float* W0, const float* W1,
                                            const float* W2, const float* W3,
                                            bf16_t* Wt) {
  const int bid = blockIdx.x, tid = threadIdx.x;
  __shared__ float t[32][33];
  const int wz = bid >> 10, t2 = bid & 1023;
  const float* W = (wz == 0) ? W0 : (wz == 1) ? W1 : (wz == 2) ? W2 : W3;
  bf16_t* o = Wt + (size_t)wz * 1024 * 1024;
  const int n0 = (t2 & 31) * 32, k0 = (t2 >> 5) * 32;
  const int tx = tid & 31, ty = tid >> 5;
#pragma unroll
  for (int i = 0; i < 4; i++)
    t[ty + 8 * i][tx] = W[(size_t)(k0 + ty + 8 * i) * 1024 + n0 + tx];
  __syncthreads();
#pragma unroll
  for (int i = 0; i < 4; i++)
    o[(size_t)(n0 + ty + 8 * i) * 1024 + k0 + tx] = (bf16_t)t[tx][ty + 8 * i];
}

// ---------------------------------------------------------------------------
// GEMM 128x128 tile, BK=64, LDS double-buffered, register-staged pipeline
// (R8 skeleton, proven). MODE 0: A is fp32 (q/k/v), converted to bf16 in
// registers at deposit time. MODE 1: A is bf16 (ctx). B always bf16 W^T.
// Grid mapping: bm = blockIdx.x (32), bn = blockIdx.y (8) -> XCD = bm%8;
// per-XCD L2 working set = 4 A-tiles + W^T (2MB).
// ---------------------------------------------------------------------------
template <int MODE>
__global__ __launch_bounds__(256) void gemm_k(
    const float* qf, const float* kf, const float* vf, const bf16_t* Actx,
    const bf16_t* Wt, const float* b0, const float* b1, const float* b2,
    bf16_t* Qh, bf16_t* Kh, bf16_t* Vt, float* Of32) {
  __shared__ bf16_t As[2][128 * 64];
  __shared__ bf16_t Bs[2][128 * 64];
  const int tid = threadIdx.x, w = tid >> 6, lane = tid & 63;
  const int bm = blockIdx.x, bn = blockIdx.y;  // XCD = bm%8
  const int wr = w >> 1, wc = w & 1, q4 = lane >> 4, lo = lane & 15;
  const int z = (MODE == 0) ? blockIdx.z : 3;
  const bf16_t* Bt = Wt + (size_t)z * 1024 * 1024;
  const float* bias = (MODE == 1) ? b0 : (z == 0) ? b0 : (z == 1) ? b1 : b2;

  f32x4 acc[4][4];
#pragma unroll
  for (int m = 0; m < 4; m++)
#pragma unroll
    for (int n = 0; n < 4; n++) acc[m][n] = (f32x4){0.f, 0.f, 0.f, 0.f};

  const int r2 = tid >> 1;         // 0..127
  const int cb = (tid & 1) * 4;    // chunk base 0 / 4
  const float* Af = (MODE == 0) ? ((z == 0) ? qf : (z == 1) ? kf : vf) : nullptr;
  const float* Arowf =
      (MODE == 0) ? Af + (size_t)(bm * 128 + r2) * 1024 : nullptr;
  const bf16_t* Arowb =
      (MODE == 1) ? Actx + (size_t)(bm * 128 + r2) * 1024 : nullptr;
  const bf16_t* Brow = Bt + (size_t)(bn * 128 + r2) * 1024;

  float4 arf[8];
  bf16x8 arb[4], br[4];
  auto loadAB = [&](int k0) {
    if constexpr (MODE == 0) {
#pragma unroll
      for (int i = 0; i < 4; i++) {
        arf[2 * i] = *(const float4*)(Arowf + k0 + (cb + i) * 8);
        arf[2 * i + 1] = *(const float4*)(Arowf + k0 + (cb + i) * 8 + 4);
      }
    } else {
#pragma unroll
      for (int i = 0; i < 4; i++)
        arb[i] = *(const bf16x8*)(Arowb + k0 + (cb + i) * 8);
    }
#pragma unroll
    for (int i = 0; i < 4; i++)
      br[i] = *(const bf16x8*)(Brow + k0 + (cb + i) * 8);
  };

  loadAB(0);
  for (int k = 0; k < 16; k++) {
    const int cur = k & 1;
    // deposit tile k (waits only on its own global loads); MODE 0 converts
    // fp32->bf16 here (same cast as the old prep -> bit-identical A)
#pragma unroll
    for (int i = 0; i < 4; i++) {
      bf16x8 av;
      if constexpr (MODE == 0) {
        float4 lo4 = arf[2 * i], hi4 = arf[2 * i + 1];
        av = (bf16x8){(bf16_t)lo4.x, (bf16_t)lo4.y, (bf16_t)lo4.z,
                      (bf16_t)lo4.w, (bf16_t)hi4.x, (bf16_t)hi4.y,
                      (bf16_t)hi4.z, (bf16_t)hi4.w};
      } else {
        av = arb[i];
      }
      *(bf16x8*)&As[cur][r2 * 64 + (((cb + i) ^ (r2 & 7)) * 8)] = av;
      *(bf16x8*)&Bs[cur][r2 * 64 + (((cb + i) ^ (r2 & 7)) * 8)] = br[i];
    }
    // prefetch tile k+1 into private regs (in flight through barrier+compute)
    if (k < 15) loadAB((k + 1) * 64);
    __syncthreads();

#pragma unroll
    for (int kc = 0; kc < 2; kc++) {
      bf16x8 af[4], bfr[4];
#pragma unroll
      for (int m = 0; m < 4; m++) {
        int rr = wr * 64 + m * 16 + lo;
        af[m] = *(const bf16x8*)&As[cur][rr * 64 + (((kc * 4 + q4) ^ (rr & 7)) * 8)];
      }
#pragma unroll
      for (int n = 0; n < 4; n++) {
        int rr = wc * 64 + n * 16 + lo;
        bfr[n] = *(const bf16x8*)&Bs[cur][rr * 64 + (((kc * 4 + q4) ^ (rr & 7)) * 8)];
      }
#pragma unroll
      for (int m = 0; m < 4; m++)
#pragma unroll
        for (int n = 0; n < 4; n++)
          acc[m][n] = MFMA16(af[m], bfr[n], acc[m][n]);
    }
    // no trailing barrier: dbuf + top-of-iter deposit make it safe
  }

#pragma unroll
  for (int m = 0; m < 4; m++) {
#pragma unroll
    for (int n = 0; n < 4; n++) {
      int rowg0 = bm * 128 + wr * 64 + m * 16 + q4 * 4;
      int colg = bn * 128 + wc * 64 + n * 16 + lo;
      float bv = bias[colg];
#pragma unroll
      for (int rg = 0; rg < 4; rg++) {
        float val = acc[m][n][rg] + bv;
        int row = rowg0 + rg;
        if (MODE == 1) {
          Of32[(size_t)row * 1024 + colg] = val;
        } else {
          int b = row >> 11, s = row & 2047;  // S=2048
          int h = colg >> 7, d = colg & 127;  // DH=128
          if (z == 0)
            Qh[(((size_t)(b * 8 + h)) * 2048 + s) * 128 + d] = (bf16_t)val;
          else if (z == 1)
            Kh[(((size_t)(b * 8 + h)) * 2048 + s) * 128 + d] = (bf16_t)val;
          else
            Vt[(((size_t)(b * 8 + h)) * 128 + d) * 2048 + s] = (bf16_t)val;
        }
      }
    }
  }
}

// ---------------------------------------------------------------------------
// Flash attention v7 (R13, proven 51.5us): R8 skeleton (512 blocks,
// t/(31-t) pairing, QBLK=64, 4 waves, reg-staged dbuf K/V), key-split
// wave map: wave (r=w>>1, kh=w&1) owns rows r*32..+31 x keys kh*32..+31.
// Ps per-wave [32 rows][stride 40]. End-of-block combine of key-half
// partials via dead staging LDS.
// ---------------------------------------------------------------------------
__global__ __launch_bounds__(256) void flash_k(const bf16_t* Qh,
                                               const bf16_t* Kh,
                                               const bf16_t* Vt, bf16_t* ctx,
                                               const int* causal_p) {
  __shared__ bf16_t sm[32768 + 4 * 1280];
  const int tid = threadIdx.x, w = tid >> 6, lane = tid & 63;
  const int q4 = lane >> 4, lo = lane & 15;
  const int r = w >> 1, kh = w & 1;  // row-group (32 rows), key-half (32 keys)
  const int n0 = blockIdx.x;
  const int u = n0 & 255, hi = n0 >> 8;
  const int bh = u & 15, p0 = u >> 4;
  const int t = hi ? (31 - p0) : p0;
  const int causal = *causal_p;
  const int kmax = causal ? t : 31;

  bf16_t* Ps = sm + 32768 + w * 1280;  // [32 rows][40], 2560B per wave

  // Q fragments: rows t*64 + r*32 + m*16 + lo, dh chunk ks*32 + q4*8.
  bf16x8 aq[2][4];
#pragma unroll
  for (int m = 0; m < 2; m++) {
    const bf16_t* qa =
        Qh + ((size_t)bh * 2048 + t * 64 + r * 32 + m * 16 + lo) * 128;
#pragma unroll
    for (int ks = 0; ks < 4; ks++)
      aq[m][ks] = *(const bf16x8*)(qa + ks * 32 + q4 * 8);
  }

  const bf16_t* Kbase = Kh + (size_t)bh * 2048 * 128;
  const bf16_t* Vbase = Vt + (size_t)bh * 128 * 2048;
  const int kr = tid >> 2, kc = (tid & 3) * 4;
  const int vd = tid >> 1, vc = (tid & 1) * 4;

  bf16x8 kreg[4], vreg[4];
  auto loadKV = [&](int kt) {
    const bf16_t* kp = Kbase + (size_t)(kt * 64 + kr) * 128;
    const bf16_t* vp = Vbase + (size_t)vd * 2048 + kt * 64;
#pragma unroll
    for (int i = 0; i < 4; i++) {
      kreg[i] = *(const bf16x8*)(kp + (kc + i) * 8);
      vreg[i] = *(const bf16x8*)(vp + (vc + i) * 8);
    }
  };

  f32x4 acc[2][8];  // partial over this wave's key-half
  f32x4 lacc[2];
#pragma unroll
  for (int m = 0; m < 2; m++) {
#pragma unroll
    for (int i = 0; i < 8; i++) acc[m][i] = (f32x4){0.f, 0.f, 0.f, 0.f};
    lacc[m] = (f32x4){0.f, 0.f, 0.f, 0.f};
  }

  const bf16_t one = (bf16_t)1.0f;
  const bf16x8 vone = {one, one, one, one, one, one, one, one};
  const float sc2 = 0.08838834764831845f * 1.44269504088896f;

  loadKV(0);
  for (int kt = 0; kt <= kmax; ++kt) {
    bf16_t* Kd = sm + (kt & 1) * 8192;
    bf16_t* Vd = sm + 16384 + (kt & 1) * 8192;
#pragma unroll
    for (int i = 0; i < 4; i++)
      *(bf16x8*)&Kd[kr * 128 + (((kc + i) ^ (kr & 7)) * 8)] = kreg[i];
#pragma unroll
    for (int i = 0; i < 4; i++)
      *(bf16x8*)&Vd[vd * 64 + (((vc + i) ^ ((vd >> 1) & 7)) * 8)] = vreg[i];
    if (kt < kmax) loadKV(kt + 1);
    __syncthreads();

    // ---- QK^T: [32 rows x 32 keys] per wave ----
    f32x4 sa[2][2];
#pragma unroll
    for (int m = 0; m < 2; m++)
#pragma unroll
      for (int nt = 0; nt < 2; nt++) sa[m][nt] = (f32x4){0.f, 0.f, 0.f, 0.f};
#pragma unroll
    for (int ks = 0; ks < 4; ks++) {
#pragma unroll
      for (int nt = 0; nt < 2; nt++) {
        int key = kh * 32 + nt * 16 + lo;
        bf16x8 bk =
            *(const bf16x8*)&Kd[key * 128 + (((ks * 4 + q4) ^ (key & 7)) * 8)];
        sa[0][nt] = MFMA16(aq[0][ks], bk, sa[0][nt]);
        sa[1][nt] = MFMA16(aq[1][ks], bk, sa[1][nt]);
      }
    }

    // ---- softmax numerator -> wave-private P [32 rows x 32 keys] ----
    const bool diag = causal && (kt == t);
#pragma unroll
    for (int m = 0; m < 2; m++) {
#pragma unroll
      for (int nt = 0; nt < 2; nt++) {
        int keyrel = kh * 32 + nt * 16 + lo;  // within 64-key tile
#pragma unroll
        for (int rg = 0; rg < 4; rg++) {
          int rowrel = r * 32 + m * 16 + q4 * 4 + rg;
          float pv = exp2f(sa[m][nt][rg] * sc2);
          if (diag && keyrel > rowrel) pv = 0.f;
          Ps[(m * 16 + q4 * 4 + rg) * 40 + nt * 16 + lo] = (bf16_t)pv;
        }
      }
    }

    // ---- P fragments (K=32 covers the wave's whole key-half) ----
    bf16x8 ap[2];
#pragma unroll
    for (int m = 0; m < 2; m++) {
      ap[m] = *(const bf16x8*)&Ps[(m * 16 + lo) * 40 + q4 * 8];
      lacc[m] = MFMA16(ap[m], vone, lacc[m]);
    }
    // ---- PV partial over keys kh*32..+31 (chunk kh*4+q4 of V rows) ----
#pragma unroll
    for (int n = 0; n < 8; n++) {
      int d = n * 16 + lo;
      int sw = (d >> 1) & 7;
      bf16x8 bv = *(const bf16x8*)&Vd[d * 64 + (((kh * 4 + q4) ^ sw) * 8)];
      acc[0][n] = MFMA16(ap[0], bv, acc[0][n]);
      acc[1][n] = MFMA16(ap[1], bv, acc[1][n]);
    }
  }

  // ---- combine key-half partials (once per block) ----
  __syncthreads();  // staging LDS now dead; Ps reads all done
  float* farena = (float*)sm;  // 8192 floats = 32KB (staging region)
  if (kh == 1) {
    int base = r * 4096 + lane * 64;
#pragma unroll
    for (int m = 0; m < 2; m++)
#pragma unroll
      for (int n = 0; n < 8; n++) {
        int c = m * 8 + n;
        *(f32x4*)&farena[base + ((c ^ (lane & 15)) & 15) * 4] = acc[m][n];
      }
    float* lp = (float*)(sm + 32768 + w * 1280);
    *(f32x4*)&lp[lane * 8] = lacc[0];
    *(f32x4*)&lp[lane * 8 + 4] = lacc[1];
  }
  __syncthreads();
  if (kh == 0) {
    int base = r * 4096 + lane * 64;
    float* lp = (float*)(sm + 32768 + (w + 1) * 1280);
    lacc[0] += *(const f32x4*)&lp[lane * 8];
    lacc[1] += *(const f32x4*)&lp[lane * 8 + 4];
#pragma unroll
    for (int m = 0; m < 2; m++)
#pragma unroll
      for (int n = 0; n < 8; n++) {
        int c = m * 8 + n;
        acc[m][n] += *(const f32x4*)&farena[base + ((c ^ (lane & 15)) & 15) * 4];
      }
    int b = bh >> 3, h = bh & 7;
#pragma unroll
    for (int m = 0; m < 2; m++) {
#pragma unroll
      for (int rg = 0; rg < 4; rg++) {
        float inv = 1.f / lacc[m][rg];
        int row = b * 2048 + t * 64 + r * 32 + m * 16 + q4 * 4 + rg;
#pragma unroll
        for (int n = 0; n < 8; n++)
          ctx[(size_t)row * 1024 + h * 128 + n * 16 + lo] =
              (bf16_t)(acc[m][n][rg] * inv);
      }
    }
  }
}

// ---------------------------------------------------------------------------
extern "C" void kernel_launch(void* const* d_in, const int* in_sizes, int n_in,
                              void* d_out, int out_size, void* d_ws,
                              size_t ws_size, hipStream_t stream) {
  const float* q = (const float*)d_in[0];
  const float* k = (const float*)d_in[1];
  const float* v = (const float*)d_in[2];
  const float* Wq = (const float*)d_in[3];
  const float* bq = (const float*)d_in[4];
  const float* Wk = (const float*)d_in[5];
  const float* bk = (const float*)d_in[6];
  const float* Wv = (const float*)d_in[7];
  const float* bv = (const float*)d_in[8];
  const float* Wo = (const float*)d_in[9];
  const float* bo = (const float*)d_in[10];
  const int* isc = (const int*)d_in[11];

  char* ws = (char*)d_ws;
  bf16_t* Wt = (bf16_t*)ws;                     // 8MB: W^T bf16 x4
  bf16_t* ctx = (bf16_t*)(ws + (8ull << 20));   // 8MB bf16 [4096,1024]
  bf16_t* Qh = (bf16_t*)(ws + (32ull << 20));   // 8MB [B,H,S,DH]
  bf16_t* Kh = (bf16_t*)(ws + (40ull << 20));   // 8MB [B,H,S,DH]
  bf16_t* Vt = (bf16_t*)(ws + (48ull << 20));   // 8MB [B,H,DH,S]

  prep<<<dim3(4096), 256, 0, stream>>>(Wq, Wk, Wv, Wo, Wt);

  gemm_k<0><<<dim3(32, 8, 3), 256, 0, stream>>>(q, k, v, nullptr, Wt, bq, bk,
                                                bv, Qh, Kh, Vt, nullptr);

  flash_k<<<dim3(512), 256, 0, stream>>>(Qh, Kh, Vt, ctx, isc);

  gemm_k<1><<<dim3(32, 8), 256, 0, stream>>>(nullptr, nullptr, nullptr, ctx,
                                             Wt, bo, nullptr, nullptr, nullptr,
                                             nullptr, nullptr, (float*)d_out);
}

// Round 8
// 221.212 us; speedup vs baseline: 1.3048x; 1.1679x over previous
//
#include <hip/hip_runtime.h>
#include <math.h>

// MultiHeadBigBirdAttention: B=2, S=2048, E=1024, H=8, DH=128
// Pipeline (bf16 MFMA 16x16x32):
//   1. prep: fused {q,k,v fp32->bf16} + {W* fp32 [K][N] -> bf16 W^T [N][K]}
//   2. gemm_qkv (grid 32x8x3): projections -> Qh/Kh [B,H,S,DH], Vt [B,H,DH,S]
//   3. flash_k: static-max flash (R13 structure, 51.5us) -> ctx bf16
//   4. gemm_out (grid 64x8): ctx @ Wo^T + bo -> d_out fp32, BM=64 tile
//
// MFMA layouts (verified learn_hip m89/m91/m120):
//   C/D: col = lane&15, row = (lane>>4)*4 + reg
//   A:   m   = lane&15, k   = (lane>>4)*8 + j
//   B:   n   = lane&15, k   = (lane>>4)*8 + j
//
// R16:
//   - R15's fp32-A fusion REVERTED (gemm0 50->95us: doubled staged bytes +
//     cvt chain on the latency-critical staging path; in latency-bound
//     loops bytes-through-registers is the cost metric, not HBM bytes).
//     Pipeline restored to R13 (best, 228.2us).
//   - gemm1 -> gemm_out with BM=64 (grid 64x8 = 512 blocks = 2/CU, was
//     256 = 1/CU). R10 counters showed gemm1 ~ gemm0 ~ 61us despite 3x
//     fewer FLOPs: 1 block/CU left its latency unhidden. Same reg-staged
//     skeleton, 2x2 wave map (32x64/wave), same XOR-swizzle family.

typedef __bf16 bf16_t;
typedef __bf16 bf16x8 __attribute__((ext_vector_type(8)));
typedef float f32x4 __attribute__((ext_vector_type(4)));

#define MFMA16(a, b, c) __builtin_amdgcn_mfma_f32_16x16x32_bf16(a, b, c, 0, 0, 0)

// ---------------------------------------------------------------------------
// prep: blocks 0..6143 convert q/k/v fp32->bf16 (8 elems/thread);
//       blocks 6144..10239 transpose the 4 weight matrices to bf16 W^T.
// ---------------------------------------------------------------------------
__global__ __launch_bounds__(256) void prep(const float* q, const float* k,
                                            const float* v, bf16_t* qb,
                                            bf16_t* kb, bf16_t* vb,
                                            const float* W0, const float* W1,
                                            const float* W2, const float* W3,
                                            bf16_t* Wt) {
  const int bid = blockIdx.x, tid = threadIdx.x;
  if (bid < 6144) {
    const int z = bid >> 11, chunk = bid & 2047;
    const float* x = (z == 0) ? q : (z == 1) ? k : v;
    bf16_t* y = (z == 0) ? qb : (z == 1) ? kb : vb;
    size_t i = ((size_t)chunk * 256 + tid) * 8;
    float4 a = *(const float4*)(x + i);
    float4 b = *(const float4*)(x + i + 4);
    bf16x8 o = {(bf16_t)a.x, (bf16_t)a.y, (bf16_t)a.z, (bf16_t)a.w,
                (bf16_t)b.x, (bf16_t)b.y, (bf16_t)b.z, (bf16_t)b.w};
    *(bf16x8*)(y + i) = o;
  } else {
    __shared__ float t[32][33];
    const int b2 = bid - 6144;
    const int wz = b2 >> 10, t2 = b2 & 1023;
    const float* W = (wz == 0) ? W0 : (wz == 1) ? W1 : (wz == 2) ? W2 : W3;
    bf16_t* o = Wt + (size_t)wz * 1024 * 1024;
    const int n0 = (t2 & 31) * 32, k0 = (t2 >> 5) * 32;
    const int tx = tid & 31, ty = tid >> 5;
#pragma unroll
    for (int i = 0; i < 4; i++)
      t[ty + 8 * i][tx] = W[(size_t)(k0 + ty + 8 * i) * 1024 + n0 + tx];
    __syncthreads();
#pragma unroll
    for (int i = 0; i < 4; i++)
      o[(size_t)(n0 + ty + 8 * i) * 1024 + k0 + tx] = (bf16_t)t[tx][ty + 8 * i];
  }
}

// ---------------------------------------------------------------------------
// gemm_qkv: 128x128 tile, BK=64, LDS double-buffered, register-staged
// pipeline (R8 skeleton, proven). Grid (bm=32, bn=8, z=3) -> XCD = bm%8;
// per-XCD L2 working set = 4 A-tiles (1MB) + W^T (2MB).
// ---------------------------------------------------------------------------
__global__ __launch_bounds__(256) void gemm_qkv(
    const bf16_t* qb, const bf16_t* kb, const bf16_t* vb, const bf16_t* Wt,
    const float* b0, const float* b1, const float* b2, bf16_t* Qh, bf16_t* Kh,
    bf16_t* Vt) {
  __shared__ bf16_t As[2][128 * 64];
  __shared__ bf16_t Bs[2][128 * 64];
  const int tid = threadIdx.x, w = tid >> 6, lane = tid & 63;
  const int bm = blockIdx.x, bn = blockIdx.y;  // XCD = bm%8
  const int wr = w >> 1, wc = w & 1, q4 = lane >> 4, lo = lane & 15;
  const int z = blockIdx.z;
  const bf16_t* A = (z == 0) ? qb : (z == 1) ? kb : vb;
  const bf16_t* Bt = Wt + (size_t)z * 1024 * 1024;
  const float* bias = (z == 0) ? b0 : (z == 1) ? b1 : b2;

  f32x4 acc[4][4];
#pragma unroll
  for (int m = 0; m < 4; m++)
#pragma unroll
    for (int n = 0; n < 4; n++) acc[m][n] = (f32x4){0.f, 0.f, 0.f, 0.f};

  const int r2 = tid >> 1;         // 0..127
  const int cb = (tid & 1) * 4;    // chunk base 0 / 4
  const bf16_t* Arow = A + (size_t)(bm * 128 + r2) * 1024;
  const bf16_t* Brow = Bt + (size_t)(bn * 128 + r2) * 1024;

  bf16x8 ar[4], br[4];
  auto loadAB = [&](int k0) {
#pragma unroll
    for (int i = 0; i < 4; i++) {
      ar[i] = *(const bf16x8*)(Arow + k0 + (cb + i) * 8);
      br[i] = *(const bf16x8*)(Brow + k0 + (cb + i) * 8);
    }
  };

  loadAB(0);
  for (int k = 0; k < 16; k++) {
    const int cur = k & 1;
    // deposit tile k (waits only on its own global loads)
#pragma unroll
    for (int i = 0; i < 4; i++) {
      *(bf16x8*)&As[cur][r2 * 64 + (((cb + i) ^ (r2 & 7)) * 8)] = ar[i];
      *(bf16x8*)&Bs[cur][r2 * 64 + (((cb + i) ^ (r2 & 7)) * 8)] = br[i];
    }
    // prefetch tile k+1 into private regs (in flight through barrier+compute)
    if (k < 15) loadAB((k + 1) * 64);
    __syncthreads();

#pragma unroll
    for (int kc = 0; kc < 2; kc++) {
      bf16x8 af[4], bfr[4];
#pragma unroll
      for (int m = 0; m < 4; m++) {
        int rr = wr * 64 + m * 16 + lo;
        af[m] = *(const bf16x8*)&As[cur][rr * 64 + (((kc * 4 + q4) ^ (rr & 7)) * 8)];
      }
#pragma unroll
      for (int n = 0; n < 4; n++) {
        int rr = wc * 64 + n * 16 + lo;
        bfr[n] = *(const bf16x8*)&Bs[cur][rr * 64 + (((kc * 4 + q4) ^ (rr & 7)) * 8)];
      }
#pragma unroll
      for (int m = 0; m < 4; m++)
#pragma unroll
        for (int n = 0; n < 4; n++)
          acc[m][n] = MFMA16(af[m], bfr[n], acc[m][n]);
    }
    // no trailing barrier: dbuf + top-of-iter deposit make it safe
  }

#pragma unroll
  for (int m = 0; m < 4; m++) {
#pragma unroll
    for (int n = 0; n < 4; n++) {
      int rowg0 = bm * 128 + wr * 64 + m * 16 + q4 * 4;
      int colg = bn * 128 + wc * 64 + n * 16 + lo;
      float bv = bias[colg];
#pragma unroll
      for (int rg = 0; rg < 4; rg++) {
        float val = acc[m][n][rg] + bv;
        int row = rowg0 + rg;
        int b = row >> 11, s = row & 2047;  // S=2048
        int h = colg >> 7, d = colg & 127;  // DH=128
        if (z == 0)
          Qh[(((size_t)(b * 8 + h)) * 2048 + s) * 128 + d] = (bf16_t)val;
        else if (z == 1)
          Kh[(((size_t)(b * 8 + h)) * 2048 + s) * 128 + d] = (bf16_t)val;
        else
          Vt[(((size_t)(b * 8 + h)) * 128 + d) * 2048 + s] = (bf16_t)val;
      }
    }
  }
}

// ---------------------------------------------------------------------------
// gemm_out: BM=64 x BN=128 tile, BK=64. Grid (64, 8) = 512 blocks = 2/CU
// (gemm1 at 256 blocks was 1/CU and fully latency-exposed). 4 waves as 2x2:
// wave (wr,wc) computes rows wr*32..+31 x cols wc*64..+63. Same reg-staged
// dbuf skeleton and XOR-swizzle family as gemm_qkv.
// ---------------------------------------------------------------------------
__global__ __launch_bounds__(256) void gemm_out(const bf16_t* ctx,
                                                const bf16_t* Wt3,
                                                const float* bo, float* Of32) {
  __shared__ bf16_t As[2][64 * 64];
  __shared__ bf16_t Bs[2][128 * 64];
  const int tid = threadIdx.x, w = tid >> 6, lane = tid & 63;
  const int bm = blockIdx.x, bn = blockIdx.y;  // XCD = bm%8
  const int wr = w >> 1, wc = w & 1, q4 = lane >> 4, lo = lane & 15;

  f32x4 acc[2][4];
#pragma unroll
  for (int m = 0; m < 2; m++)
#pragma unroll
    for (int n = 0; n < 4; n++) acc[m][n] = (f32x4){0.f, 0.f, 0.f, 0.f};

  const int r2a = tid >> 2;        // 0..63
  const int cba = (tid & 3) * 2;   // chunk base 0/2/4/6
  const int r2b = tid >> 1;        // 0..127
  const int cbb = (tid & 1) * 4;   // chunk base 0/4
  const bf16_t* Arow = ctx + (size_t)(bm * 64 + r2a) * 1024;
  const bf16_t* Brow = Wt3 + (size_t)(bn * 128 + r2b) * 1024;

  bf16x8 ar[2], br[4];
  auto loadAB = [&](int k0) {
#pragma unroll
    for (int i = 0; i < 2; i++)
      ar[i] = *(const bf16x8*)(Arow + k0 + (cba + i) * 8);
#pragma unroll
    for (int i = 0; i < 4; i++)
      br[i] = *(const bf16x8*)(Brow + k0 + (cbb + i) * 8);
  };

  loadAB(0);
  for (int k = 0; k < 16; k++) {
    const int cur = k & 1;
#pragma unroll
    for (int i = 0; i < 2; i++)
      *(bf16x8*)&As[cur][r2a * 64 + (((cba + i) ^ (r2a & 7)) * 8)] = ar[i];
#pragma unroll
    for (int i = 0; i < 4; i++)
      *(bf16x8*)&Bs[cur][r2b * 64 + (((cbb + i) ^ (r2b & 7)) * 8)] = br[i];
    if (k < 15) loadAB((k + 1) * 64);
    __syncthreads();

#pragma unroll
    for (int kc = 0; kc < 2; kc++) {
      bf16x8 af[2], bfr[4];
#pragma unroll
      for (int m = 0; m < 2; m++) {
        int rr = wr * 32 + m * 16 + lo;
        af[m] = *(const bf16x8*)&As[cur][rr * 64 + (((kc * 4 + q4) ^ (rr & 7)) * 8)];
      }
#pragma unroll
      for (int n = 0; n < 4; n++) {
        int rr = wc * 64 + n * 16 + lo;
        bfr[n] = *(const bf16x8*)&Bs[cur][rr * 64 + (((kc * 4 + q4) ^ (rr & 7)) * 8)];
      }
#pragma unroll
      for (int m = 0; m < 2; m++)
#pragma unroll
        for (int n = 0; n < 4; n++)
          acc[m][n] = MFMA16(af[m], bfr[n], acc[m][n]);
    }
  }

#pragma unroll
  for (int m = 0; m < 2; m++) {
#pragma unroll
    for (int n = 0; n < 4; n++) {
      int rowg0 = bm * 64 + wr * 32 + m * 16 + q4 * 4;
      int colg = bn * 128 + wc * 64 + n * 16 + lo;
      float bv = bo[colg];
#pragma unroll
      for (int rg = 0; rg < 4; rg++)
        Of32[(size_t)(rowg0 + rg) * 1024 + colg] = acc[m][n][rg] + bv;
    }
  }
}

// ---------------------------------------------------------------------------
// Flash attention v7 (R13, proven 51.5us): R8 skeleton (512 blocks,
// t/(31-t) pairing, QBLK=64, 4 waves, reg-staged dbuf K/V), key-split
// wave map: wave (r=w>>1, kh=w&1) owns rows r*32..+31 x keys kh*32..+31.
// Ps per-wave [32 rows][stride 40]. End-of-block combine of key-half
// partials via dead staging LDS.
// ---------------------------------------------------------------------------
__global__ __launch_bounds__(256) void flash_k(const bf16_t* Qh,
                                               const bf16_t* Kh,
                                               const bf16_t* Vt, bf16_t* ctx,
                                               const int* causal_p) {
  __shared__ bf16_t sm[32768 + 4 * 1280];
  const int tid = threadIdx.x, w = tid >> 6, lane = tid & 63;
  const int q4 = lane >> 4, lo = lane & 15;
  const int r = w >> 1, kh = w & 1;  // row-group (32 rows), key-half (32 keys)
  const int n0 = blockIdx.x;
  const int u = n0 & 255, hi = n0 >> 8;
  const int bh = u & 15, p0 = u >> 4;
  const int t = hi ? (31 - p0) : p0;
  const int causal = *causal_p;
  const int kmax = causal ? t : 31;

  bf16_t* Ps = sm + 32768 + w * 1280;  // [32 rows][40], 2560B per wave

  // Q fragments: rows t*64 + r*32 + m*16 + lo, dh chunk ks*32 + q4*8.
  bf16x8 aq[2][4];
#pragma unroll
  for (int m = 0; m < 2; m++) {
    const bf16_t* qa =
        Qh + ((size_t)bh * 2048 + t * 64 + r * 32 + m * 16 + lo) * 128;
#pragma unroll
    for (int ks = 0; ks < 4; ks++)
      aq[m][ks] = *(const bf16x8*)(qa + ks * 32 + q4 * 8);
  }

  const bf16_t* Kbase = Kh + (size_t)bh * 2048 * 128;
  const bf16_t* Vbase = Vt + (size_t)bh * 128 * 2048;
  const int kr = tid >> 2, kc = (tid & 3) * 4;
  const int vd = tid >> 1, vc = (tid & 1) * 4;

  bf16x8 kreg[4], vreg[4];
  auto loadKV = [&](int kt) {
    const bf16_t* kp = Kbase + (size_t)(kt * 64 + kr) * 128;
    const bf16_t* vp = Vbase + (size_t)vd * 2048 + kt * 64;
#pragma unroll
    for (int i = 0; i < 4; i++) {
      kreg[i] = *(const bf16x8*)(kp + (kc + i) * 8);
      vreg[i] = *(const bf16x8*)(vp + (vc + i) * 8);
    }
  };

  f32x4 acc[2][8];  // partial over this wave's key-half
  f32x4 lacc[2];
#pragma unroll
  for (int m = 0; m < 2; m++) {
#pragma unroll
    for (int i = 0; i < 8; i++) acc[m][i] = (f32x4){0.f, 0.f, 0.f, 0.f};
    lacc[m] = (f32x4){0.f, 0.f, 0.f, 0.f};
  }

  const bf16_t one = (bf16_t)1.0f;
  const bf16x8 vone = {one, one, one, one, one, one, one, one};
  const float sc2 = 0.08838834764831845f * 1.44269504088896f;

  loadKV(0);
  for (int kt = 0; kt <= kmax; ++kt) {
    bf16_t* Kd = sm + (kt & 1) * 8192;
    bf16_t* Vd = sm + 16384 + (kt & 1) * 8192;
#pragma unroll
    for (int i = 0; i < 4; i++)
      *(bf16x8*)&Kd[kr * 128 + (((kc + i) ^ (kr & 7)) * 8)] = kreg[i];
#pragma unroll
    for (int i = 0; i < 4; i++)
      *(bf16x8*)&Vd[vd * 64 + (((vc + i) ^ ((vd >> 1) & 7)) * 8)] = vreg[i];
    if (kt < kmax) loadKV(kt + 1);
    __syncthreads();

    // ---- QK^T: [32 rows x 32 keys] per wave ----
    f32x4 sa[2][2];
#pragma unroll
    for (int m = 0; m < 2; m++)
#pragma unroll
      for (int nt = 0; nt < 2; nt++) sa[m][nt] = (f32x4){0.f, 0.f, 0.f, 0.f};
#pragma unroll
    for (int ks = 0; ks < 4; ks++) {
#pragma unroll
      for (int nt = 0; nt < 2; nt++) {
        int key = kh * 32 + nt * 16 + lo;
        bf16x8 bk =
            *(const bf16x8*)&Kd[key * 128 + (((ks * 4 + q4) ^ (key & 7)) * 8)];
        sa[0][nt] = MFMA16(aq[0][ks], bk, sa[0][nt]);
        sa[1][nt] = MFMA16(aq[1][ks], bk, sa[1][nt]);
      }
    }

    // ---- softmax numerator -> wave-private P [32 rows x 32 keys] ----
    const bool diag = causal && (kt == t);
#pragma unroll
    for (int m = 0; m < 2; m++) {
#pragma unroll
      for (int nt = 0; nt < 2; nt++) {
        int keyrel = kh * 32 + nt * 16 + lo;  // within 64-key tile
#pragma unroll
        for (int rg = 0; rg < 4; rg++) {
          int rowrel = r * 32 + m * 16 + q4 * 4 + rg;
          float pv = exp2f(sa[m][nt][rg] * sc2);
          if (diag && keyrel > rowrel) pv = 0.f;
          Ps[(m * 16 + q4 * 4 + rg) * 40 + nt * 16 + lo] = (bf16_t)pv;
        }
      }
    }

    // ---- P fragments (K=32 covers the wave's whole key-half) ----
    bf16x8 ap[2];
#pragma unroll
    for (int m = 0; m < 2; m++) {
      ap[m] = *(const bf16x8*)&Ps[(m * 16 + lo) * 40 + q4 * 8];
      lacc[m] = MFMA16(ap[m], vone, lacc[m]);
    }
    // ---- PV partial over keys kh*32..+31 (chunk kh*4+q4 of V rows) ----
#pragma unroll
    for (int n = 0; n < 8; n++) {
      int d = n * 16 + lo;
      int sw = (d >> 1) & 7;
      bf16x8 bv = *(const bf16x8*)&Vd[d * 64 + (((kh * 4 + q4) ^ sw) * 8)];
      acc[0][n] = MFMA16(ap[0], bv, acc[0][n]);
      acc[1][n] = MFMA16(ap[1], bv, acc[1][n]);
    }
  }

  // ---- combine key-half partials (once per block) ----
  __syncthreads();  // staging LDS now dead; Ps reads all done
  float* farena = (float*)sm;  // 8192 floats = 32KB (staging region)
  if (kh == 1) {
    int base = r * 4096 + lane * 64;
#pragma unroll
    for (int m = 0; m < 2; m++)
#pragma unroll
      for (int n = 0; n < 8; n++) {
        int c = m * 8 + n;
        *(f32x4*)&farena[base + ((c ^ (lane & 15)) & 15) * 4] = acc[m][n];
      }
    float* lp = (float*)(sm + 32768 + w * 1280);
    *(f32x4*)&lp[lane * 8] = lacc[0];
    *(f32x4*)&lp[lane * 8 + 4] = lacc[1];
  }
  __syncthreads();
  if (kh == 0) {
    int base = r * 4096 + lane * 64;
    float* lp = (float*)(sm + 32768 + (w + 1) * 1280);
    lacc[0] += *(const f32x4*)&lp[lane * 8];
    lacc[1] += *(const f32x4*)&lp[lane * 8 + 4];
#pragma unroll
    for (int m = 0; m < 2; m++)
#pragma unroll
      for (int n = 0; n < 8; n++) {
        int c = m * 8 + n;
        acc[m][n] += *(const f32x4*)&farena[base + ((c ^ (lane & 15)) & 15) * 4];
      }
    int b = bh >> 3, h = bh & 7;
#pragma unroll
    for (int m = 0; m < 2; m++) {
#pragma unroll
      for (int rg = 0; rg < 4; rg++) {
        float inv = 1.f / lacc[m][rg];
        int row = b * 2048 + t * 64 + r * 32 + m * 16 + q4 * 4 + rg;
#pragma unroll
        for (int n = 0; n < 8; n++)
          ctx[(size_t)row * 1024 + h * 128 + n * 16 + lo] =
              (bf16_t)(acc[m][n][rg] * inv);
      }
    }
  }
}

// ---------------------------------------------------------------------------
extern "C" void kernel_launch(void* const* d_in, const int* in_sizes, int n_in,
                              void* d_out, int out_size, void* d_ws,
                              size_t ws_size, hipStream_t stream) {
  const float* q = (const float*)d_in[0];
  const float* k = (const float*)d_in[1];
  const float* v = (const float*)d_in[2];
  const float* Wq = (const float*)d_in[3];
  const float* bq = (const float*)d_in[4];
  const float* Wk = (const float*)d_in[5];
  const float* bk = (const float*)d_in[6];
  const float* Wv = (const float*)d_in[7];
  const float* bv = (const float*)d_in[8];
  const float* Wo = (const float*)d_in[9];
  const float* bo = (const float*)d_in[10];
  const int* isc = (const int*)d_in[11];

  char* ws = (char*)d_ws;
  bf16_t* Wt = (bf16_t*)ws;                     // 8MB: W^T bf16 x4
  bf16_t* qb = (bf16_t*)(ws + (8ull << 20));    // 8MB
  bf16_t* kb = (bf16_t*)(ws + (16ull << 20));   // 8MB
  bf16_t* vb = (bf16_t*)(ws + (24ull << 20));   // 8MB
  bf16_t* Qh = (bf16_t*)(ws + (32ull << 20));   // 8MB [B,H,S,DH]
  bf16_t* Kh = (bf16_t*)(ws + (40ull << 20));   // 8MB [B,H,S,DH]
  bf16_t* Vt = (bf16_t*)(ws + (48ull << 20));   // 8MB [B,H,DH,S]
  bf16_t* ctx = (bf16_t*)(ws + (8ull << 20));   // reuse qb

  prep<<<dim3(10240), 256, 0, stream>>>(q, k, v, qb, kb, vb, Wq, Wk, Wv, Wo, Wt);

  gemm_qkv<<<dim3(32, 8, 3), 256, 0, stream>>>(qb, kb, vb, Wt, bq, bk, bv, Qh,
                                               Kh, Vt);

  flash_k<<<dim3(512), 256, 0, stream>>>(Qh, Kh, Vt, ctx, isc);

  gemm_out<<<dim3(64, 8), 256, 0, stream>>>(ctx, Wt + 3ull * 1024 * 1024, bo,
                                            (float*)d_out);
}